// Round 4
// baseline (348.039 us; speedup 1.0000x reference)
//
#include <hip/hip_runtime.h>
#include <hip/hip_bf16.h>
#include <math.h>

// ---------- types ----------
typedef __attribute__((ext_vector_type(8))) short bf16x8;   // 8 bf16 in 4 VGPRs
typedef __attribute__((ext_vector_type(4))) float f32x4;

// ---------- helpers ----------
__device__ __forceinline__ unsigned short f2bf_rne(float f) {
    union { float f; unsigned u; } x; x.f = f;
    unsigned r = x.u + 0x7FFFu + ((x.u >> 16) & 1u);
    return (unsigned short)(r >> 16);
}
__device__ __forceinline__ float bf2f(unsigned short h) {
    union { unsigned u; float f; } x; x.u = ((unsigned)h) << 16;
    return x.f;
}

// 4 consecutive elements per lane (transposed-MFMA epilogue): 8B bf16 / 16B f32
__device__ __forceinline__ void store4(unsigned short* p, float v0, float v1, float v2, float v3) {
    ushort4 o; o.x = f2bf_rne(v0); o.y = f2bf_rne(v1); o.z = f2bf_rne(v2); o.w = f2bf_rne(v3);
    *(ushort4*)p = o;          // 8 B store, gn0 % 4 == 0 -> aligned
}
__device__ __forceinline__ void store4(float* p, float v0, float v1, float v2, float v3) {
    float4 o; o.x = v0; o.y = v1; o.z = v2; o.w = v3;
    *(float4*)p = o;           // 16 B store
}

__device__ __forceinline__ void async_copy16(const void* g, void* l) {
    __builtin_amdgcn_global_load_lds(
        (const __attribute__((address_space(1))) void*)g,
        (__attribute__((address_space(3))) void*)l, 16, 0, 0);
}

// ---------- fused fp32 -> bf16 converts (x, w_qkv, w_out in one launch) ----------
__global__ __launch_bounds__(256) void cvt_all(
    const float* __restrict__ x,  const float* __restrict__ wq, const float* __restrict__ wo,
    unsigned short* __restrict__ xb, unsigned short* __restrict__ wqb, unsigned short* __restrict__ wob,
    int n4x, int n4q, int n4o)
{
    int j = blockIdx.x * 256 + threadIdx.x;
    const float* in; unsigned short* out;
    if (j < n4x) { in = x; out = xb; }
    else {
        j -= n4x;
        if (j < n4q) { in = wq; out = wqb; }
        else { j -= n4q; if (j >= n4o) return; in = wo; out = wob; }
    }
    float4 v = ((const float4*)in)[j];
    ushort4 o;
    o.x = f2bf_rne(v.x); o.y = f2bf_rne(v.y);
    o.z = f2bf_rne(v.z); o.w = f2bf_rne(v.w);
    ((ushort4*)out)[j] = o;
}

// ---------- NT bf16 GEMM: C[m,n] = scale * sum_k A[m,k]*B[n,k] + bias[n] ----------
// 128x128 tile, BK=64, 256 threads = 4 waves (2x2), 64x64 per wave,
// 4x4 MFMA 16x16x32 tiles per wave, two K-halves per LDS stage.
// LDS XOR-swizzled in 16B granules (conflict-free, verified R2: SQ_LDS_BANK_CONFLICT=0).
// MFMA operands SWAPPED (D = B-frag x A-frag = C^T fragment): a lane's 4 acc
// values are 4 CONSECUTIVE n -> 8B/16B contiguous stores (R3: WRITE 100->76 MB).
// NOTE R3: __launch_bounds__(256,4) forced VGPR 76->64 and 4 blocks/CU ->
// proportional stall increase (MfmaUtil 31->26) + L2 thrash (FETCH 122->131 MB).
// Keep plain 256: default alloc (~76 VGPR, 3 blocks/CU) is the sweet spot.
template <typename OutT>
__global__ __launch_bounds__(256) void gemm_nt_bf16(
    const unsigned short* __restrict__ A, int lda, long long strideA,
    const unsigned short* __restrict__ B, int ldb, long long strideB,
    OutT* __restrict__ C, int ldc, long long strideC,
    const float* __restrict__ bias, float scale, int K)
{
    __shared__ unsigned short shA[128 * 64];
    __shared__ unsigned short shB[128 * 64];

    const int t    = threadIdx.x;
    const int lane = t & 63;
    const int wave = t >> 6;
    const int wm   = (wave & 1) * 64;   // wave row offset in tile
    const int wn   = (wave >> 1) * 64;  // wave col offset in tile
    const int quad = lane >> 4;
    const int l16  = lane & 15;

    const long long batch = blockIdx.z;
    A += batch * strideA;
    B += batch * strideB;
    C += batch * strideC;

    const long long tileM = (long long)blockIdx.y * 128;
    const long long tileN = (long long)blockIdx.x * 128;

    f32x4 acc[4][4];
#pragma unroll
    for (int i = 0; i < 4; ++i)
#pragma unroll
        for (int j = 0; j < 4; ++j)
#pragma unroll
            for (int r = 0; r < 4; ++r) acc[i][j][r] = 0.0f;

    for (int k0 = 0; k0 < K; k0 += 64) {
        __syncthreads();   // previous iter's frags consumed before overwrite
#pragma unroll
        for (int p = 0; p < 4; ++p) {
            const int g   = p * 256 + t;        // LDS granule 0..1023 (lane-ordered)
            const int row = g >> 3;             // 0..127
            const int kg  = (g & 7) ^ (row & 7);// swizzled source k-granule
            async_copy16(A + (tileM + row) * (long long)lda + k0 + kg * 8, &shA[g << 3]);
            async_copy16(B + (tileN + row) * (long long)ldb + k0 + kg * 8, &shB[g << 3]);
        }
        __syncthreads();   // compiler drains vmcnt(0) before barrier

#pragma unroll 1           // keep only one K-half's fragments live (VGPR cap)
        for (int h = 0; h < 2; ++h) {
            bf16x8 af[4], bfr[4];
#pragma unroll
            for (int mi = 0; mi < 4; ++mi) {
                const int row = wm + mi * 16 + l16;
                const int kg  = ((h << 2) | quad) ^ (row & 7);
                af[mi] = *(const bf16x8*)(&shA[row * 64 + kg * 8]);
            }
#pragma unroll
            for (int ni = 0; ni < 4; ++ni) {
                const int row = wn + ni * 16 + l16;
                const int kg  = ((h << 2) | quad) ^ (row & 7);
                bfr[ni] = *(const bf16x8*)(&shB[row * 64 + kg * 8]);
            }
#pragma unroll
            for (int mi = 0; mi < 4; ++mi)
#pragma unroll
                for (int ni = 0; ni < 4; ++ni)
                    acc[mi][ni] = __builtin_amdgcn_mfma_f32_16x16x32_bf16(
                        bfr[ni], af[mi], acc[mi][ni], 0, 0, 0);   // operands swapped: D = C^T frag
        }
    }

    // epilogue: D holds C^T tile: lane -> m = l16 (fixed row), n = quad*4 + {0..3}
#pragma unroll
    for (int mi = 0; mi < 4; ++mi) {
        const long long gm = tileM + wm + mi * 16 + l16;
#pragma unroll
        for (int ni = 0; ni < 4; ++ni) {
            const long long gn0 = tileN + wn + ni * 16 + quad * 4;
            float b0 = 0.f, b1 = 0.f, b2 = 0.f, b3 = 0.f;
            if (bias) {
                float4 bv = *(const float4*)&bias[gn0];
                b0 = bv.x; b1 = bv.y; b2 = bv.z; b3 = bv.w;
            }
            const f32x4 a = acc[mi][ni];
            store4(C + gm * (long long)ldc + gn0,
                   a[0] * scale + b0, a[1] * scale + b1,
                   a[2] * scale + b2, a[3] * scale + b3);
        }
    }
}

// ---------- row softmax in place on [rows][1024] bf16 ----------
__global__ __launch_bounds__(256) void softmax_inplace(unsigned short* __restrict__ att) {
    const long long row = blockIdx.x;
    unsigned short* p = att + row * 1024;
    const int t = threadIdx.x;
    const int wave = t >> 6, lane = t & 63;
    __shared__ float red[4];

    float v[4];
    float mx = -1e30f;
#pragma unroll
    for (int i = 0; i < 4; ++i) { v[i] = bf2f(p[t + i * 256]); mx = fmaxf(mx, v[i]); }
#pragma unroll
    for (int o = 32; o > 0; o >>= 1) mx = fmaxf(mx, __shfl_xor(mx, o));
    if (lane == 0) red[wave] = mx;
    __syncthreads();
    mx = fmaxf(fmaxf(red[0], red[1]), fmaxf(red[2], red[3]));

    float s = 0.f;
#pragma unroll
    for (int i = 0; i < 4; ++i) { v[i] = __expf(v[i] - mx); s += v[i]; }
#pragma unroll
    for (int o = 32; o > 0; o >>= 1) s += __shfl_xor(s, o);
    __syncthreads();   // red[] reuse
    if (lane == 0) red[wave] = s;
    __syncthreads();
    s = red[0] + red[1] + red[2] + red[3];
    const float inv = 1.0f / s;
#pragma unroll
    for (int i = 0; i < 4; ++i) p[t + i * 256] = f2bf_rne(v[i] * inv);
}

// ---------- V transpose: vt[b][d][k] = qkv[b][k][1536+d] ----------
__global__ __launch_bounds__(256) void transpose_v(const unsigned short* __restrict__ qkv,
                                                   unsigned short* __restrict__ vt) {
    __shared__ unsigned short tile[32][33];
    const int b  = blockIdx.z;
    const int k0 = blockIdx.x * 32;
    const int d0 = blockIdx.y * 32;
    const int x  = threadIdx.x;  // 32
    const int y  = threadIdx.y;  // 8
    const unsigned short* src = qkv + (long long)b * 1024 * 2304;
#pragma unroll
    for (int j = 0; j < 4; ++j) {
        int k = k0 + y + j * 8;
        tile[y + j * 8][x] = src[(long long)k * 2304 + 1536 + d0 + x];
    }
    __syncthreads();
    unsigned short* dst = vt + (long long)b * 768 * 1024;
#pragma unroll
    for (int j = 0; j < 4; ++j) {
        int d = d0 + y + j * 8;
        dst[(long long)d * 1024 + k0 + x] = tile[x][y + j * 8];
    }
}

// ---------- launcher ----------
extern "C" void kernel_launch(void* const* d_in, const int* in_sizes, int n_in,
                              void* d_out, int out_size, void* d_ws, size_t ws_size,
                              hipStream_t stream) {
    (void)in_sizes; (void)n_in; (void)out_size; (void)ws_size;

    const float* x     = (const float*)d_in[0];
    const float* w_qkv = (const float*)d_in[1];
    const float* b_qkv = (const float*)d_in[2];
    const float* w_out = (const float*)d_in[3];
    const float* b_out = (const float*)d_in[4];
    float* out = (float*)d_out;

    const int B = 16, S = 1024, D = 768;
    const long long MS = (long long)B * S;  // 16384 rows

    // workspace layout (bf16 = ushort), all 16B aligned
    unsigned short* xb   = (unsigned short*)d_ws;          // [16384][768]
    unsigned short* wqb  = xb   + MS * D;                  // [2304][768]
    unsigned short* wob  = wqb  + 3LL * D * D;             // [768][768]
    unsigned short* qkvb = wob  + (long long)D * D;        // [16384][2304]
    unsigned short* att  = qkvb + MS * 3 * D;              // [16][1024][1024]
    unsigned short* vt   = att  + (long long)B * S * S;    // [16][768][1024]
    unsigned short* ob   = vt   + (long long)B * D * S;    // [16384][768]

    // 1) converts (single launch)
    {
        const int n4x = (int)(MS * D / 4);
        const int n4q = 3 * D * D / 4;
        const int n4o = D * D / 4;
        const int tot = n4x + n4q + n4o;
        cvt_all<<<(tot + 255) / 256, 256, 0, stream>>>(x, w_qkv, w_out, xb, wqb, wob,
                                                      n4x, n4q, n4o);
    }

    // 2) QKV = x @ Wqkv^T + b   [16384, 2304]
    gemm_nt_bf16<unsigned short><<<dim3(3 * D / 128, MS / 128, 1), 256, 0, stream>>>(
        xb, D, 0, wqb, D, 0, qkvb, 3 * D, 0, b_qkv, 1.0f, D);

    // 3) logits = scale * Q @ K^T   per batch [1024, 1024]
    const float scale = 0.03608439182435162f;  // 1/sqrt(768)
    gemm_nt_bf16<unsigned short><<<dim3(S / 128, S / 128, B), 256, 0, stream>>>(
        qkvb,     3 * D, (long long)S * 3 * D,
        qkvb + D, 3 * D, (long long)S * 3 * D,
        att, S, (long long)S * S, nullptr, scale, D);

    // 4) softmax rows in place
    softmax_inplace<<<(int)MS, 256, 0, stream>>>(att);

    // 5) vt[b][d][k] = v[b][k][d]
    transpose_v<<<dim3(S / 32, D / 32, B), dim3(32, 8), 0, stream>>>(qkvb, vt);

    // 6) O = P @ V   per batch [1024, 768]
    gemm_nt_bf16<unsigned short><<<dim3(D / 128, S / 128, B), 256, 0, stream>>>(
        att, S, (long long)S * S,
        vt,  S, (long long)D * S,
        ob,  D, (long long)S * D, nullptr, 1.0f, S);

    // 7) out = O @ Wout^T + b   [16384, 768] fp32
    gemm_nt_bf16<float><<<dim3(D / 128, MS / 128, 1), 256, 0, stream>>>(
        ob, D, 0, wob, D, 0, out, D, 0, b_out, 1.0f, D);
}

// Round 5
// 334.963 us; speedup vs baseline: 1.0390x; 1.0390x over previous
//
#include <hip/hip_runtime.h>
#include <hip/hip_bf16.h>
#include <math.h>

// ---------- types ----------
typedef __attribute__((ext_vector_type(8))) short bf16x8;   // 8 bf16 in 4 VGPRs
typedef __attribute__((ext_vector_type(4))) float f32x4;

// ---------- helpers ----------
__device__ __forceinline__ unsigned short f2bf_rne(float f) {
    union { float f; unsigned u; } x; x.f = f;
    unsigned r = x.u + 0x7FFFu + ((x.u >> 16) & 1u);
    return (unsigned short)(r >> 16);
}
__device__ __forceinline__ float bf2f(unsigned short h) {
    union { unsigned u; float f; } x; x.u = ((unsigned)h) << 16;
    return x.f;
}

// 4 consecutive elements per lane (transposed-MFMA epilogue): 8B bf16 / 16B f32
__device__ __forceinline__ void store4(unsigned short* p, float v0, float v1, float v2, float v3) {
    ushort4 o; o.x = f2bf_rne(v0); o.y = f2bf_rne(v1); o.z = f2bf_rne(v2); o.w = f2bf_rne(v3);
    *(ushort4*)p = o;          // 8 B store, gn0 % 4 == 0 -> aligned
}
__device__ __forceinline__ void store4(float* p, float v0, float v1, float v2, float v3) {
    float4 o; o.x = v0; o.y = v1; o.z = v2; o.w = v3;
    *(float4*)p = o;           // 16 B store
}

__device__ __forceinline__ void async_copy16(const void* g, void* l) {
    __builtin_amdgcn_global_load_lds(
        (const __attribute__((address_space(1))) void*)g,
        (__attribute__((address_space(3))) void*)l, 16, 0, 0);
}

// ---------- fused fp32 -> bf16 converts (x, w_qkv, w_out in one launch) ----------
__global__ __launch_bounds__(256) void cvt_all(
    const float* __restrict__ x,  const float* __restrict__ wq, const float* __restrict__ wo,
    unsigned short* __restrict__ xb, unsigned short* __restrict__ wqb, unsigned short* __restrict__ wob,
    int n4x, int n4q, int n4o)
{
    int j = blockIdx.x * 256 + threadIdx.x;
    const float* in; unsigned short* out;
    if (j < n4x) { in = x; out = xb; }
    else {
        j -= n4x;
        if (j < n4q) { in = wq; out = wqb; }
        else { j -= n4q; if (j >= n4o) return; in = wo; out = wob; }
    }
    float4 v = ((const float4*)in)[j];
    ushort4 o;
    o.x = f2bf_rne(v.x); o.y = f2bf_rne(v.y);
    o.z = f2bf_rne(v.z); o.w = f2bf_rne(v.w);
    ((ushort4*)out)[j] = o;
}

// ---------- NT bf16 GEMM: C[m,n] = f( scale * sum_k A[m,k]*B[n,k] ) + bias[n] ----------
// 128x128 tile, BK=64, 256 threads = 4 waves (2x2), 64x64 per wave,
// 4x4 MFMA 16x16x32 tiles per wave, two K-halves per LDS stage.
// LDS XOR-swizzled in 16B granules (conflict-free, verified R2: SQ_LDS_BANK_CONFLICT=0).
// MFMA operands SWAPPED (D = B-frag x A-frag = C^T fragment): a lane's 4 acc
// values are 4 CONSECUTIVE n -> 8B/16B contiguous stores (R3/R4: WRITE 100->74 MB).
// Plain __launch_bounds__(256): R3 showed (256,4) squeezes VGPRs -> stall + L2 thrash.
//
// Fused softmax split (R5):
//   DO_EXP:    store exp(scale*acc) and atomicAdd per-row partial sums into
//              rowsum[] (logits ~N(0,1): max|s|~6, exp<=~400 -> no max-subtract
//              needed; shift-invariance makes this exact in fp32).
//   DO_RSCALE: multiply row m by 1/rowsum[m]  (O = P~ V then row-scale == softmax V).
template <typename OutT, bool DO_EXP, bool DO_RSCALE>
__global__ __launch_bounds__(256) void gemm_nt_bf16(
    const unsigned short* __restrict__ A, int lda, long long strideA,
    const unsigned short* __restrict__ B, int ldb, long long strideB,
    OutT* __restrict__ C, int ldc, long long strideC,
    const float* __restrict__ bias, float scale, int K,
    float* __restrict__ rowsum, const float* __restrict__ rscale)
{
    __shared__ unsigned short shA[128 * 64];
    __shared__ unsigned short shB[128 * 64];

    const int t    = threadIdx.x;
    const int lane = t & 63;
    const int wave = t >> 6;
    const int wm   = (wave & 1) * 64;   // wave row offset in tile
    const int wn   = (wave >> 1) * 64;  // wave col offset in tile
    const int quad = lane >> 4;
    const int l16  = lane & 15;

    const long long batch = blockIdx.z;
    A += batch * strideA;
    B += batch * strideB;
    C += batch * strideC;

    const long long tileM = (long long)blockIdx.y * 128;
    const long long tileN = (long long)blockIdx.x * 128;
    const long long rowsPerBatch = (long long)gridDim.y * 128;

    f32x4 acc[4][4];
#pragma unroll
    for (int i = 0; i < 4; ++i)
#pragma unroll
        for (int j = 0; j < 4; ++j)
#pragma unroll
            for (int r = 0; r < 4; ++r) acc[i][j][r] = 0.0f;

    for (int k0 = 0; k0 < K; k0 += 64) {
        __syncthreads();   // previous iter's frags consumed before overwrite
#pragma unroll
        for (int p = 0; p < 4; ++p) {
            const int g   = p * 256 + t;        // LDS granule 0..1023 (lane-ordered)
            const int row = g >> 3;             // 0..127
            const int kg  = (g & 7) ^ (row & 7);// swizzled source k-granule
            async_copy16(A + (tileM + row) * (long long)lda + k0 + kg * 8, &shA[g << 3]);
            async_copy16(B + (tileN + row) * (long long)ldb + k0 + kg * 8, &shB[g << 3]);
        }
        __syncthreads();   // compiler drains vmcnt(0) before barrier

#pragma unroll 1           // keep only one K-half's fragments live (VGPR cap)
        for (int h = 0; h < 2; ++h) {
            bf16x8 af[4], bfr[4];
#pragma unroll
            for (int mi = 0; mi < 4; ++mi) {
                const int row = wm + mi * 16 + l16;
                const int kg  = ((h << 2) | quad) ^ (row & 7);
                af[mi] = *(const bf16x8*)(&shA[row * 64 + kg * 8]);
            }
#pragma unroll
            for (int ni = 0; ni < 4; ++ni) {
                const int row = wn + ni * 16 + l16;
                const int kg  = ((h << 2) | quad) ^ (row & 7);
                bfr[ni] = *(const bf16x8*)(&shB[row * 64 + kg * 8]);
            }
#pragma unroll
            for (int mi = 0; mi < 4; ++mi)
#pragma unroll
                for (int ni = 0; ni < 4; ++ni)
                    acc[mi][ni] = __builtin_amdgcn_mfma_f32_16x16x32_bf16(
                        bfr[ni], af[mi], acc[mi][ni], 0, 0, 0);   // operands swapped: D = C^T frag
        }
    }

    // epilogue: D holds C^T tile: lane -> m = l16 (fixed row), n = quad*4 + {0..3}
#pragma unroll
    for (int mi = 0; mi < 4; ++mi) {
        const long long gm = tileM + wm + mi * 16 + l16;
        float w = scale;
        if (DO_RSCALE) w = scale / rscale[batch * rowsPerBatch + gm];
        float rsum = 0.0f;
#pragma unroll
        for (int ni = 0; ni < 4; ++ni) {
            const long long gn0 = tileN + wn + ni * 16 + quad * 4;
            float b0 = 0.f, b1 = 0.f, b2 = 0.f, b3 = 0.f;
            if (bias) {
                float4 bv = *(const float4*)&bias[gn0];
                b0 = bv.x; b1 = bv.y; b2 = bv.z; b3 = bv.w;
            }
            const f32x4 a = acc[mi][ni];
            float v0, v1, v2, v3;
            if (DO_EXP) {
                v0 = __expf(a[0] * scale); v1 = __expf(a[1] * scale);
                v2 = __expf(a[2] * scale); v3 = __expf(a[3] * scale);
                rsum += (v0 + v1) + (v2 + v3);
            } else {
                v0 = a[0] * w + b0; v1 = a[1] * w + b1;
                v2 = a[2] * w + b2; v3 = a[3] * w + b3;
            }
            store4(C + gm * (long long)ldc + gn0, v0, v1, v2, v3);
        }
        if (DO_EXP) {
            // lanes sharing l16 (quad bits = lane bits 4,5) hold disjoint n-ranges
            rsum += __shfl_xor(rsum, 16);
            rsum += __shfl_xor(rsum, 32);
            if (quad == 0)
                atomicAdd(&rowsum[batch * rowsPerBatch + gm], rsum);
        }
    }
}

// ---------- V transpose: vt[b][d][k] = qkv[b][k][1536+d] ----------
__global__ __launch_bounds__(256) void transpose_v(const unsigned short* __restrict__ qkv,
                                                   unsigned short* __restrict__ vt) {
    __shared__ unsigned short tile[32][33];
    const int b  = blockIdx.z;
    const int k0 = blockIdx.x * 32;
    const int d0 = blockIdx.y * 32;
    const int x  = threadIdx.x;  // 32
    const int y  = threadIdx.y;  // 8
    const unsigned short* src = qkv + (long long)b * 1024 * 2304;
#pragma unroll
    for (int j = 0; j < 4; ++j) {
        int k = k0 + y + j * 8;
        tile[y + j * 8][x] = src[(long long)k * 2304 + 1536 + d0 + x];
    }
    __syncthreads();
    unsigned short* dst = vt + (long long)b * 768 * 1024;
#pragma unroll
    for (int j = 0; j < 4; ++j) {
        int d = d0 + y + j * 8;
        dst[(long long)d * 1024 + k0 + x] = tile[x][y + j * 8];
    }
}

// ---------- launcher ----------
extern "C" void kernel_launch(void* const* d_in, const int* in_sizes, int n_in,
                              void* d_out, int out_size, void* d_ws, size_t ws_size,
                              hipStream_t stream) {
    (void)in_sizes; (void)n_in; (void)out_size; (void)ws_size;

    const float* x     = (const float*)d_in[0];
    const float* w_qkv = (const float*)d_in[1];
    const float* b_qkv = (const float*)d_in[2];
    const float* w_out = (const float*)d_in[3];
    const float* b_out = (const float*)d_in[4];
    float* out = (float*)d_out;

    const int B = 16, S = 1024, D = 768;
    const long long MS = (long long)B * S;  // 16384 rows

    // workspace layout (bf16 = ushort), all 16B aligned
    unsigned short* xb   = (unsigned short*)d_ws;          // [16384][768]
    unsigned short* wqb  = xb   + MS * D;                  // [2304][768]
    unsigned short* wob  = wqb  + 3LL * D * D;             // [768][768]
    unsigned short* qkvb = wob  + (long long)D * D;        // [16384][2304]
    unsigned short* att  = qkvb + MS * 3 * D;              // [16][1024][1024] exp(logits)
    unsigned short* vt   = att  + (long long)B * S * S;    // [16][768][1024]
    unsigned short* ob   = vt   + (long long)B * D * S;    // [16384][768]
    float*          rsum = (float*)(ob + MS * D);          // [16][1024]

    // 1) converts (single launch) + zero the rowsum accumulator
    {
        const int n4x = (int)(MS * D / 4);
        const int n4q = 3 * D * D / 4;
        const int n4o = D * D / 4;
        const int tot = n4x + n4q + n4o;
        cvt_all<<<(tot + 255) / 256, 256, 0, stream>>>(x, w_qkv, w_out, xb, wqb, wob,
                                                      n4x, n4q, n4o);
        hipMemsetAsync(rsum, 0, (size_t)B * S * sizeof(float), stream);
    }

    // 2) QKV = x @ Wqkv^T + b   [16384, 2304]
    gemm_nt_bf16<unsigned short, false, false><<<dim3(3 * D / 128, MS / 128, 1), 256, 0, stream>>>(
        xb, D, 0, wqb, D, 0, qkvb, 3 * D, 0, b_qkv, 1.0f, D, nullptr, nullptr);

    // 3) att = exp(scale * Q @ K^T) per batch [1024,1024]; rowsum accumulated via atomics
    const float scale = 0.03608439182435162f;  // 1/sqrt(768)
    gemm_nt_bf16<unsigned short, true, false><<<dim3(S / 128, S / 128, B), 256, 0, stream>>>(
        qkvb,     3 * D, (long long)S * 3 * D,
        qkvb + D, 3 * D, (long long)S * 3 * D,
        att, S, (long long)S * S, nullptr, scale, D, rsum, nullptr);

    // 4) vt[b][d][k] = v[b][k][d]
    transpose_v<<<dim3(S / 32, D / 32, B), dim3(32, 8), 0, stream>>>(qkvb, vt);

    // 5) O = (P~ @ V) * 1/rowsum per row   per batch [1024, 768]
    gemm_nt_bf16<unsigned short, false, true><<<dim3(D / 128, S / 128, B), 256, 0, stream>>>(
        att, S, (long long)S * S,
        vt,  S, (long long)D * S,
        ob,  D, (long long)S * D, nullptr, 1.0f, S, nullptr, rsum);

    // 6) out = O @ Wout^T + b   [16384, 768] fp32
    gemm_nt_bf16<float, false, false><<<dim3(D / 128, MS / 128, 1), 256, 0, stream>>>(
        ob, D, 0, wob, D, 0, out, D, 0, b_out, 1.0f, D, nullptr, nullptr);
}

// Round 6
// 328.551 us; speedup vs baseline: 1.0593x; 1.0195x over previous
//
#include <hip/hip_runtime.h>
#include <hip/hip_bf16.h>
#include <math.h>

// ---------- types ----------
typedef __attribute__((ext_vector_type(8))) short bf16x8;   // 8 bf16 in 4 VGPRs
typedef __attribute__((ext_vector_type(8))) unsigned short u16x8;
typedef __attribute__((ext_vector_type(4))) float f32x4;

// ---------- helpers ----------
__device__ __forceinline__ unsigned short f2bf_rne(float f) {
    union { float f; unsigned u; } x; x.f = f;
    unsigned r = x.u + 0x7FFFu + ((x.u >> 16) & 1u);
    return (unsigned short)(r >> 16);
}

// 4 consecutive elements per lane (transposed-MFMA epilogue): 8B bf16 / 16B f32
__device__ __forceinline__ void store4(unsigned short* p, float v0, float v1, float v2, float v3) {
    ushort4 o; o.x = f2bf_rne(v0); o.y = f2bf_rne(v1); o.z = f2bf_rne(v2); o.w = f2bf_rne(v3);
    *(ushort4*)p = o;          // 8 B store, gn0 % 4 == 0 -> aligned
}
__device__ __forceinline__ void store4(float* p, float v0, float v1, float v2, float v3) {
    float4 o; o.x = v0; o.y = v1; o.z = v2; o.w = v3;
    *(float4*)p = o;           // 16 B store
}

// ---------- fused fp32 -> bf16 converts + rowsum zeroing (one launch) ----------
__global__ __launch_bounds__(256) void cvt_all(
    const float* __restrict__ x,  const float* __restrict__ wq, const float* __restrict__ wo,
    unsigned short* __restrict__ xb, unsigned short* __restrict__ wqb, unsigned short* __restrict__ wob,
    float* __restrict__ rsum,
    int n4x, int n4q, int n4o, int n4r)
{
    int j = blockIdx.x * 256 + threadIdx.x;
    const float* in; unsigned short* out;
    if (j < n4x) { in = x; out = xb; }
    else {
        j -= n4x;
        if (j < n4q) { in = wq; out = wqb; }
        else {
            j -= n4q;
            if (j < n4o) { in = wo; out = wob; }
            else {
                j -= n4o;
                if (j < n4r) { float4 z = {0.f, 0.f, 0.f, 0.f}; ((float4*)rsum)[j] = z; }
                return;
            }
        }
    }
    float4 v = ((const float4*)in)[j];
    ushort4 o;
    o.x = f2bf_rne(v.x); o.y = f2bf_rne(v.y);
    o.z = f2bf_rne(v.z); o.w = f2bf_rne(v.w);
    ((ushort4*)out)[j] = o;
}

// ---------- NT bf16 GEMM: C[m,n] = f( scale * sum_k A[m,k]*B[n,k] ) + bias[n] ----------
// 128x128 tile, BK=64, 256 threads = 4 waves (2x2), 64x64 per wave,
// 4x4 MFMA 16x16x32 tiles per wave, two K-halves per LDS stage.
// LDS XOR-swizzled in 16B granules (conflict-free, verified R2: SQ_LDS_BANK_CONFLICT=0).
// MFMA operands SWAPPED (D = B-frag x A-frag = C^T fragment) -> contiguous 8B/16B stores.
// Plain __launch_bounds__(256): R3 showed (256,4) squeezes VGPRs -> stall + L2 thrash.
//
// R6: REGISTER-STAGED PIPELINE (replaces global_load_lds). m97's structural ~20%
// stall is the s_waitcnt vmcnt(0) the compiler must emit before each s_barrier
// when staging via global_load_lds. Here the K-loop is:
//   barrier -> ds_write staged regs (vmcnt wait lands HERE, one full MFMA
//   section after issue) -> barrier -> issue next tile's global loads into
//   regs -> 32 MFMA from LDS.
// Loads for tile k+1 are in flight during tile k's compute; the pre-compute
// barrier drains only lgkm (fast ds_writes). LDS byte image identical to the
// async path, so fragment reads/swizzle are unchanged.
//
// Fused softmax split (R5, verified):
//   DO_EXP:    store exp(scale*acc), atomicAdd per-row partials into rowsum[]
//              (logits ~N(0,1) -> no max-subtract needed; exact by shift-invariance).
//   DO_RSCALE: multiply row m by 1/rowsum[m].
template <typename OutT, bool DO_EXP, bool DO_RSCALE>
__global__ __launch_bounds__(256) void gemm_nt_bf16(
    const unsigned short* __restrict__ A, int lda, long long strideA,
    const unsigned short* __restrict__ B, int ldb, long long strideB,
    OutT* __restrict__ C, int ldc, long long strideC,
    const float* __restrict__ bias, float scale, int K,
    float* __restrict__ rowsum, const float* __restrict__ rscale)
{
    __shared__ unsigned short shA[128 * 64];
    __shared__ unsigned short shB[128 * 64];

    const int t    = threadIdx.x;
    const int lane = t & 63;
    const int wave = t >> 6;
    const int wm   = (wave & 1) * 64;   // wave row offset in tile
    const int wn   = (wave >> 1) * 64;  // wave col offset in tile
    const int quad = lane >> 4;
    const int l16  = lane & 15;

    const long long batch = blockIdx.z;
    A += batch * strideA;
    B += batch * strideB;
    C += batch * strideC;

    const long long tileM = (long long)blockIdx.y * 128;
    const long long tileN = (long long)blockIdx.x * 128;
    const long long rowsPerBatch = (long long)gridDim.y * 128;

    // per-thread global source pointers for the 4 A- and 4 B-granules it stages;
    // swizzled mapping identical to the old async path: LDS granule g holds
    // global granule (row = g>>3, kg = (g&7) ^ (row&7)).
    const unsigned short* gA[4];
    const unsigned short* gB[4];
#pragma unroll
    for (int p = 0; p < 4; ++p) {
        const int g   = p * 256 + t;
        const int row = g >> 3;
        const int kg  = (g & 7) ^ (row & 7);
        gA[p] = A + (tileM + row) * (long long)lda + kg * 8;
        gB[p] = B + (tileN + row) * (long long)ldb + kg * 8;
    }

    f32x4 acc[4][4];
#pragma unroll
    for (int i = 0; i < 4; ++i)
#pragma unroll
        for (int j = 0; j < 4; ++j)
#pragma unroll
            for (int r = 0; r < 4; ++r) acc[i][j][r] = 0.0f;

    // prologue: stage tile 0 into registers
    u16x8 rA[4], rB[4];
#pragma unroll
    for (int p = 0; p < 4; ++p) {
        rA[p] = *(const u16x8*)(gA[p]);
        rB[p] = *(const u16x8*)(gB[p]);
    }

    for (int k0 = 64; k0 <= K; k0 += 64) {
        __syncthreads();   // all waves done reading prior LDS tile
#pragma unroll
        for (int p = 0; p < 4; ++p) {   // vmcnt wait for rA/rB lands here
            *(u16x8*)(&shA[(p * 256 + t) * 8]) = rA[p];
            *(u16x8*)(&shB[(p * 256 + t) * 8]) = rB[p];
        }
        __syncthreads();   // drains lgkm only (fast)

        if (k0 < K) {      // issue next tile's loads; they fly during the MFMAs below
#pragma unroll
            for (int p = 0; p < 4; ++p) {
                rA[p] = *(const u16x8*)(gA[p] + k0);
                rB[p] = *(const u16x8*)(gB[p] + k0);
            }
        }

#pragma unroll 1           // keep only one K-half's fragments live (VGPR cap)
        for (int h = 0; h < 2; ++h) {
            bf16x8 af[4], bfr[4];
#pragma unroll
            for (int mi = 0; mi < 4; ++mi) {
                const int row = wm + mi * 16 + l16;
                const int kg  = ((h << 2) | quad) ^ (row & 7);
                af[mi] = *(const bf16x8*)(&shA[row * 64 + kg * 8]);
            }
#pragma unroll
            for (int ni = 0; ni < 4; ++ni) {
                const int row = wn + ni * 16 + l16;
                const int kg  = ((h << 2) | quad) ^ (row & 7);
                bfr[ni] = *(const bf16x8*)(&shB[row * 64 + kg * 8]);
            }
#pragma unroll
            for (int mi = 0; mi < 4; ++mi)
#pragma unroll
                for (int ni = 0; ni < 4; ++ni)
                    acc[mi][ni] = __builtin_amdgcn_mfma_f32_16x16x32_bf16(
                        bfr[ni], af[mi], acc[mi][ni], 0, 0, 0);   // operands swapped: D = C^T frag
        }
    }

    // epilogue: D holds C^T tile: lane -> m = l16 (fixed row), n = quad*4 + {0..3}
#pragma unroll
    for (int mi = 0; mi < 4; ++mi) {
        const long long gm = tileM + wm + mi * 16 + l16;
        float w = scale;
        if (DO_RSCALE) w = scale / rscale[batch * rowsPerBatch + gm];
        float rsum = 0.0f;
#pragma unroll
        for (int ni = 0; ni < 4; ++ni) {
            const long long gn0 = tileN + wn + ni * 16 + quad * 4;
            float b0 = 0.f, b1 = 0.f, b2 = 0.f, b3 = 0.f;
            if (bias) {
                float4 bv = *(const float4*)&bias[gn0];
                b0 = bv.x; b1 = bv.y; b2 = bv.z; b3 = bv.w;
            }
            const f32x4 a = acc[mi][ni];
            float v0, v1, v2, v3;
            if (DO_EXP) {
                v0 = __expf(a[0] * scale); v1 = __expf(a[1] * scale);
                v2 = __expf(a[2] * scale); v3 = __expf(a[3] * scale);
                rsum += (v0 + v1) + (v2 + v3);
            } else {
                v0 = a[0] * w + b0; v1 = a[1] * w + b1;
                v2 = a[2] * w + b2; v3 = a[3] * w + b3;
            }
            store4(C + gm * (long long)ldc + gn0, v0, v1, v2, v3);
        }
        if (DO_EXP) {
            // lanes sharing l16 (quad bits = lane bits 4,5) hold disjoint n-ranges
            rsum += __shfl_xor(rsum, 16);
            rsum += __shfl_xor(rsum, 32);
            if (quad == 0)
                atomicAdd(&rowsum[batch * rowsPerBatch + gm], rsum);
        }
    }
}

// ---------- V transpose: vt[b][d][k] = qkv[b][k][1536+d] ----------
__global__ __launch_bounds__(256) void transpose_v(const unsigned short* __restrict__ qkv,
                                                   unsigned short* __restrict__ vt) {
    __shared__ unsigned short tile[32][33];
    const int b  = blockIdx.z;
    const int k0 = blockIdx.x * 32;
    const int d0 = blockIdx.y * 32;
    const int x  = threadIdx.x;  // 32
    const int y  = threadIdx.y;  // 8
    const unsigned short* src = qkv + (long long)b * 1024 * 2304;
#pragma unroll
    for (int j = 0; j < 4; ++j) {
        int k = k0 + y + j * 8;
        tile[y + j * 8][x] = src[(long long)k * 2304 + 1536 + d0 + x];
    }
    __syncthreads();
    unsigned short* dst = vt + (long long)b * 768 * 1024;
#pragma unroll
    for (int j = 0; j < 4; ++j) {
        int d = d0 + y + j * 8;
        dst[(long long)d * 1024 + k0 + x] = tile[x][y + j * 8];
    }
}

// ---------- launcher ----------
extern "C" void kernel_launch(void* const* d_in, const int* in_sizes, int n_in,
                              void* d_out, int out_size, void* d_ws, size_t ws_size,
                              hipStream_t stream) {
    (void)in_sizes; (void)n_in; (void)out_size; (void)ws_size;

    const float* x     = (const float*)d_in[0];
    const float* w_qkv = (const float*)d_in[1];
    const float* b_qkv = (const float*)d_in[2];
    const float* w_out = (const float*)d_in[3];
    const float* b_out = (const float*)d_in[4];
    float* out = (float*)d_out;

    const int B = 16, S = 1024, D = 768;
    const long long MS = (long long)B * S;  // 16384 rows

    // workspace layout (bf16 = ushort), all 16B aligned
    unsigned short* xb   = (unsigned short*)d_ws;          // [16384][768]
    unsigned short* wqb  = xb   + MS * D;                  // [2304][768]
    unsigned short* wob  = wqb  + 3LL * D * D;             // [768][768]
    unsigned short* qkvb = wob  + (long long)D * D;        // [16384][2304]
    unsigned short* att  = qkvb + MS * 3 * D;              // [16][1024][1024] exp(logits)
    unsigned short* vt   = att  + (long long)B * S * S;    // [16][768][1024]
    unsigned short* ob   = vt   + (long long)B * D * S;    // [16384][768]
    float*          rsum = (float*)(ob + MS * D);          // [16][1024]

    // 1) converts + rowsum zeroing (single launch)
    {
        const int n4x = (int)(MS * D / 4);
        const int n4q = 3 * D * D / 4;
        const int n4o = D * D / 4;
        const int n4r = B * S / 4;
        const int tot = n4x + n4q + n4o + n4r;
        cvt_all<<<(tot + 255) / 256, 256, 0, stream>>>(x, w_qkv, w_out, xb, wqb, wob,
                                                      rsum, n4x, n4q, n4o, n4r);
    }

    // 2) QKV = x @ Wqkv^T + b   [16384, 2304]
    gemm_nt_bf16<unsigned short, false, false><<<dim3(3 * D / 128, MS / 128, 1), 256, 0, stream>>>(
        xb, D, 0, wqb, D, 0, qkvb, 3 * D, 0, b_qkv, 1.0f, D, nullptr, nullptr);

    // 3) att = exp(scale * Q @ K^T) per batch [1024,1024]; rowsum accumulated via atomics
    const float scale = 0.03608439182435162f;  // 1/sqrt(768)
    gemm_nt_bf16<unsigned short, true, false><<<dim3(S / 128, S / 128, B), 256, 0, stream>>>(
        qkvb,     3 * D, (long long)S * 3 * D,
        qkvb + D, 3 * D, (long long)S * 3 * D,
        att, S, (long long)S * S, nullptr, scale, D, rsum, nullptr);

    // 4) vt[b][d][k] = v[b][k][d]
    transpose_v<<<dim3(S / 32, D / 32, B), dim3(32, 8), 0, stream>>>(qkvb, vt);

    // 5) O = (P~ @ V) * 1/rowsum per row   per batch [1024, 768]
    gemm_nt_bf16<unsigned short, false, true><<<dim3(D / 128, S / 128, B), 256, 0, stream>>>(
        att, S, (long long)S * S,
        vt,  S, (long long)D * S,
        ob,  D, (long long)S * D, nullptr, 1.0f, S, nullptr, rsum);

    // 6) out = O @ Wout^T + b   [16384, 768] fp32
    gemm_nt_bf16<float, false, false><<<dim3(D / 128, MS / 128, 1), 256, 0, stream>>>(
        ob, D, 0, wob, D, 0, out, D, 0, b_out, 1.0f, D, nullptr, nullptr);
}

// Round 7
// 317.277 us; speedup vs baseline: 1.0970x; 1.0355x over previous
//
#include <hip/hip_runtime.h>
#include <hip/hip_bf16.h>
#include <math.h>

// ---------- types ----------
typedef __attribute__((ext_vector_type(8))) short bf16x8;   // 8 bf16 in 4 VGPRs
typedef __attribute__((ext_vector_type(4))) float f32x4;

// ---------- helpers ----------
__device__ __forceinline__ unsigned short f2bf_rne(float f) {
    union { float f; unsigned u; } x; x.f = f;
    unsigned r = x.u + 0x7FFFu + ((x.u >> 16) & 1u);
    return (unsigned short)(r >> 16);
}

// 4 consecutive elements per lane (transposed-MFMA epilogue): 8B bf16 / 16B f32
__device__ __forceinline__ void store4(unsigned short* p, float v0, float v1, float v2, float v3) {
    ushort4 o; o.x = f2bf_rne(v0); o.y = f2bf_rne(v1); o.z = f2bf_rne(v2); o.w = f2bf_rne(v3);
    *(ushort4*)p = o;          // 8 B store, gn0 % 4 == 0 -> aligned
}
__device__ __forceinline__ void store4(float* p, float v0, float v1, float v2, float v3) {
    float4 o; o.x = v0; o.y = v1; o.z = v2; o.w = v3;
    *(float4*)p = o;           // 16 B store
}

__device__ __forceinline__ void async_copy16(const void* g, void* l) {
    __builtin_amdgcn_global_load_lds(
        (const __attribute__((address_space(1))) void*)g,
        (__attribute__((address_space(3))) void*)l, 16, 0, 0);
}

// ---------- fused fp32 -> bf16 converts + rowsum zeroing (one launch) ----------
__global__ __launch_bounds__(256) void cvt_all(
    const float* __restrict__ x,  const float* __restrict__ wq, const float* __restrict__ wo,
    unsigned short* __restrict__ xb, unsigned short* __restrict__ wqb, unsigned short* __restrict__ wob,
    float* __restrict__ rsum,
    int n4x, int n4q, int n4o, int n4r)
{
    int j = blockIdx.x * 256 + threadIdx.x;
    const float* in; unsigned short* out;
    if (j < n4x) { in = x; out = xb; }
    else {
        j -= n4x;
        if (j < n4q) { in = wq; out = wqb; }
        else {
            j -= n4q;
            if (j < n4o) { in = wo; out = wob; }
            else {
                j -= n4o;
                if (j < n4r) { float4 z = {0.f, 0.f, 0.f, 0.f}; ((float4*)rsum)[j] = z; }
                return;
            }
        }
    }
    float4 v = ((const float4*)in)[j];
    ushort4 o;
    o.x = f2bf_rne(v.x); o.y = f2bf_rne(v.y);
    o.z = f2bf_rne(v.z); o.w = f2bf_rne(v.w);
    ((ushort4*)out)[j] = o;
}

// ---------- NT bf16 GEMM: C[m,n] = f( scale * sum_k A[m,k]*B[n,k] ) + bias[n] ----------
// 128x128 tile, BK=64, 256 threads = 4 waves (2x2), 64x64 per wave,
// 4x4 MFMA 16x16x32 tiles per wave, two K-halves per LDS stage.
// Staging: global_load_lds width=16 (R6 showed register-staged pipeline is
// neutral-to-worse: the binding cost is LDS issue bandwidth, not load latency,
// and buffer_load staging fetched +14 MB more from HBM).
// LDS XOR-swizzled in 16B granules (conflict-free, verified R2: SQ_LDS_BANK_CONFLICT=0).
// MFMA operands SWAPPED (D = B-frag x A-frag = C^T fragment) -> contiguous 8B/16B stores.
// Plain __launch_bounds__(256): R3 showed (256,4) squeezes VGPRs -> stall + L2 thrash.
//
// Epilogue fusions:
//   DO_EXP:    store exp(scale*acc), atomicAdd per-row partials into rowsum[]
//              (logits ~N(0,1) -> no max-subtract needed; exact by shift-invariance).
//   DO_RSCALE: multiply row m by 1/rowsum[m]  (O = P~V then row-scale == softmax V).
//   DO_VT:     blocks with tileN >= 1536 (the V third of QKV output) write
//              vt[b][d][k] TRANSPOSED instead of C: lane's l16 spans 16
//              consecutive k -> 32B contiguous segments; per block each d-row
//              receives 128 consecutive k (L2 coalesces before writeback).
//              Deletes the standalone transpose kernel + 25 MB of C writes.
template <typename OutT, bool DO_EXP, bool DO_RSCALE, bool DO_VT>
__global__ __launch_bounds__(256) void gemm_nt_bf16(
    const unsigned short* __restrict__ A, int lda, long long strideA,
    const unsigned short* __restrict__ B, int ldb, long long strideB,
    OutT* __restrict__ C, int ldc, long long strideC,
    const float* __restrict__ bias, float scale, int K,
    float* __restrict__ rowsum, const float* __restrict__ rscale,
    unsigned short* __restrict__ vtp)
{
    __shared__ unsigned short shA[128 * 64];
    __shared__ unsigned short shB[128 * 64];

    const int t    = threadIdx.x;
    const int lane = t & 63;
    const int wave = t >> 6;
    const int wm   = (wave & 1) * 64;   // wave row offset in tile
    const int wn   = (wave >> 1) * 64;  // wave col offset in tile
    const int quad = lane >> 4;
    const int l16  = lane & 15;

    const long long batch = blockIdx.z;
    A += batch * strideA;
    B += batch * strideB;
    C += batch * strideC;

    const long long tileM = (long long)blockIdx.y * 128;
    const long long tileN = (long long)blockIdx.x * 128;
    const long long rowsPerBatch = (long long)gridDim.y * 128;

    f32x4 acc[4][4];
#pragma unroll
    for (int i = 0; i < 4; ++i)
#pragma unroll
        for (int j = 0; j < 4; ++j)
#pragma unroll
            for (int r = 0; r < 4; ++r) acc[i][j][r] = 0.0f;

    for (int k0 = 0; k0 < K; k0 += 64) {
        __syncthreads();   // previous iter's frags consumed before overwrite
#pragma unroll
        for (int p = 0; p < 4; ++p) {
            const int g   = p * 256 + t;        // LDS granule 0..1023 (lane-ordered)
            const int row = g >> 3;             // 0..127
            const int kg  = (g & 7) ^ (row & 7);// swizzled source k-granule
            async_copy16(A + (tileM + row) * (long long)lda + k0 + kg * 8, &shA[g << 3]);
            async_copy16(B + (tileN + row) * (long long)ldb + k0 + kg * 8, &shB[g << 3]);
        }
        __syncthreads();   // compiler drains vmcnt(0) before barrier

#pragma unroll 1           // keep only one K-half's fragments live (VGPR cap)
        for (int h = 0; h < 2; ++h) {
            bf16x8 af[4], bfr[4];
#pragma unroll
            for (int mi = 0; mi < 4; ++mi) {
                const int row = wm + mi * 16 + l16;
                const int kg  = ((h << 2) | quad) ^ (row & 7);
                af[mi] = *(const bf16x8*)(&shA[row * 64 + kg * 8]);
            }
#pragma unroll
            for (int ni = 0; ni < 4; ++ni) {
                const int row = wn + ni * 16 + l16;
                const int kg  = ((h << 2) | quad) ^ (row & 7);
                bfr[ni] = *(const bf16x8*)(&shB[row * 64 + kg * 8]);
            }
#pragma unroll
            for (int mi = 0; mi < 4; ++mi)
#pragma unroll
                for (int ni = 0; ni < 4; ++ni)
                    acc[mi][ni] = __builtin_amdgcn_mfma_f32_16x16x32_bf16(
                        bfr[ni], af[mi], acc[mi][ni], 0, 0, 0);   // operands swapped: D = C^T frag
        }
    }

    // epilogue: D holds C^T tile: lane -> m = l16 (fixed row), n = quad*4 + {0..3}
    const bool vt_block = DO_VT && (tileN >= 1536);
#pragma unroll
    for (int mi = 0; mi < 4; ++mi) {
        const long long gm = tileM + wm + mi * 16 + l16;
        float w = scale;
        if (DO_RSCALE) w = scale / rscale[batch * rowsPerBatch + gm];
        float rsum = 0.0f;
#pragma unroll
        for (int ni = 0; ni < 4; ++ni) {
            const long long gn0 = tileN + wn + ni * 16 + quad * 4;
            float b0 = 0.f, b1 = 0.f, b2 = 0.f, b3 = 0.f;
            if (bias) {
                float4 bv = *(const float4*)&bias[gn0];
                b0 = bv.x; b1 = bv.y; b2 = bv.z; b3 = bv.w;
            }
            const f32x4 a = acc[mi][ni];
            float v0, v1, v2, v3;
            if (DO_EXP) {
                v0 = __expf(a[0] * scale); v1 = __expf(a[1] * scale);
                v2 = __expf(a[2] * scale); v3 = __expf(a[3] * scale);
                rsum += (v0 + v1) + (v2 + v3);
            } else {
                v0 = a[0] * w + b0; v1 = a[1] * w + b1;
                v2 = a[2] * w + b2; v3 = a[3] * w + b3;
            }
            if (vt_block) {
                // vt[b][d][k]: d = gn0-1536+r, b = gm>>10, k = gm&1023
                const long long b_   = gm >> 10;
                const long long kin  = gm & 1023;
                unsigned short* vp = vtp + (b_ * 768 + (gn0 - 1536)) * 1024 + kin;
                vp[0]        = f2bf_rne(v0);
                vp[1024]     = f2bf_rne(v1);
                vp[2 * 1024] = f2bf_rne(v2);
                vp[3 * 1024] = f2bf_rne(v3);
            } else {
                store4(C + gm * (long long)ldc + gn0, v0, v1, v2, v3);
            }
        }
        if (DO_EXP) {
            // lanes sharing l16 (quad bits = lane bits 4,5) hold disjoint n-ranges
            rsum += __shfl_xor(rsum, 16);
            rsum += __shfl_xor(rsum, 32);
            if (quad == 0)
                atomicAdd(&rowsum[batch * rowsPerBatch + gm], rsum);
        }
    }
}

// ---------- launcher ----------
extern "C" void kernel_launch(void* const* d_in, const int* in_sizes, int n_in,
                              void* d_out, int out_size, void* d_ws, size_t ws_size,
                              hipStream_t stream) {
    (void)in_sizes; (void)n_in; (void)out_size; (void)ws_size;

    const float* x     = (const float*)d_in[0];
    const float* w_qkv = (const float*)d_in[1];
    const float* b_qkv = (const float*)d_in[2];
    const float* w_out = (const float*)d_in[3];
    const float* b_out = (const float*)d_in[4];
    float* out = (float*)d_out;

    const int B = 16, S = 1024, D = 768;
    const long long MS = (long long)B * S;  // 16384 rows

    // workspace layout (bf16 = ushort), all 16B aligned
    unsigned short* xb   = (unsigned short*)d_ws;          // [16384][768]
    unsigned short* wqb  = xb   + MS * D;                  // [2304][768]
    unsigned short* wob  = wqb  + 3LL * D * D;             // [768][768]
    unsigned short* qkvb = wob  + (long long)D * D;        // [16384][2304] (V third unused)
    unsigned short* att  = qkvb + MS * 3 * D;              // [16][1024][1024] exp(logits)
    unsigned short* vt   = att  + (long long)B * S * S;    // [16][768][1024]
    unsigned short* ob   = vt   + (long long)B * D * S;    // [16384][768]
    float*          rsum = (float*)(ob + MS * D);          // [16][1024]

    // 1) converts + rowsum zeroing (single launch)
    {
        const int n4x = (int)(MS * D / 4);
        const int n4q = 3 * D * D / 4;
        const int n4o = D * D / 4;
        const int n4r = B * S / 4;
        const int tot = n4x + n4q + n4o + n4r;
        cvt_all<<<(tot + 255) / 256, 256, 0, stream>>>(x, w_qkv, w_out, xb, wqb, wob,
                                                      rsum, n4x, n4q, n4o, n4r);
    }

    // 2) QKV = x @ Wqkv^T + b  [16384, 2304]; V third written TRANSPOSED to vt
    gemm_nt_bf16<unsigned short, false, false, true><<<dim3(3 * D / 128, MS / 128, 1), 256, 0, stream>>>(
        xb, D, 0, wqb, D, 0, qkvb, 3 * D, 0, b_qkv, 1.0f, D, nullptr, nullptr, vt);

    // 3) att = exp(scale * Q @ K^T) per batch [1024,1024]; rowsum via atomics
    const float scale = 0.03608439182435162f;  // 1/sqrt(768)
    gemm_nt_bf16<unsigned short, true, false, false><<<dim3(S / 128, S / 128, B), 256, 0, stream>>>(
        qkvb,     3 * D, (long long)S * 3 * D,
        qkvb + D, 3 * D, (long long)S * 3 * D,
        att, S, (long long)S * S, nullptr, scale, D, rsum, nullptr, nullptr);

    // 4) O = (P~ @ V) * 1/rowsum per row   per batch [1024, 768]
    gemm_nt_bf16<unsigned short, false, true, false><<<dim3(D / 128, S / 128, B), 256, 0, stream>>>(
        att, S, (long long)S * S,
        vt,  S, (long long)D * S,
        ob,  D, (long long)S * D, nullptr, 1.0f, S, nullptr, rsum, nullptr);

    // 5) out = O @ Wout^T + b   [16384, 768] fp32
    gemm_nt_bf16<float, false, false, false><<<dim3(D / 128, MS / 128, 1), 256, 0, stream>>>(
        ob, D, 0, wob, D, 0, out, D, 0, b_out, 1.0f, D, nullptr, nullptr, nullptr);
}